// Round 6
// baseline (203.967 us; speedup 1.0000x reference)
//
#include <hip/hip_runtime.h>

// Problem dims
#define BN 8
#define BC 128
#define BH 56
#define BW 56
#define HW 3136
#define NTAP 35
// u16 offsets inside ws:
#define WS_WC 71680                   // stage-2 Wc fragments [WS_WC, WS_WC+4096)
#define WS_FLAGS (1u << 20)           // u16 offset of barrier flags (2 MB in)
#define MAGIC 0x9E3779B9u

typedef unsigned short u16;
typedef unsigned int u32;
typedef __bf16 bf16x8 __attribute__((ext_vector_type(8)));
typedef float f32x4 __attribute__((ext_vector_type(4)));

__device__ __forceinline__ u16 f2b(float f) {
    unsigned u = __float_as_uint(f);
    return (u16)((u + 0x7FFFu + ((u >> 16) & 1u)) >> 16);  // RNE
}
__device__ __forceinline__ u32 pack2(float a, float b) {
    return (u32)f2b(a) | ((u32)f2b(b) << 16);
}

// conv_fused v6: single PLAIN launch; prep_w fused via a software grid
// barrier (v5's hipLaunchCooperativeKernel never executed under graph
// capture -> all-zero output; API abandoned).
// Barrier safety: 448 blocks, LDS 68KB -> 2 blocks/CU, VGPR<=128 -> 16
// waves/CU => capacity 512 blocks >= 448, so all blocks schedulable while
// others spin (deadlock-free). Flags live in ws (re-poisoned each iter,
// stream-ordered before us) so MAGIC from a prior iter can't leak -- and if
// the harness skips re-poisoning, stale-MAGIC passthrough is harmless
// because weight writers rewrite bit-identical bytes.
// Phase A: blocks 0..147 write one ws weight element/thread (148*512 =
// 75776 = WS_WC+4096 exactly, same math as prep_w); all blocks run the
// weight-independent x prologue. threadfence -> syncthreads -> release
// flag; spin on all 448 flags; acquire threadfence (cross-XCD L2 inv).
// Phase B: unchanged v4 pipeline (verified 85.4us).
// LDS layout (bytes):
#define COLW 40                       // u16 per col (32 data + 8 pad)
#define XSBUF 32000                   // xs[5][80][COLW] u16
#define U32BUF 8000                   // XSBUF/4
#define Y3_OFF 64000                  // y3T[64][40] u16 = 5120
#define SMEM_SZ 69632                 // 69120 + 512 slack (benign masked-lane
                                      // col-overrun reads); 2 blocks/CU

__global__ __launch_bounds__(512, 4) void conv_fused(
    const float* __restrict__ x, const float* __restrict__ w3,
    const float* __restrict__ w4, const float* __restrict__ w5,
    u16* __restrict__ ws, float* __restrict__ out)
{
    __shared__ __align__(16) char smem[SMEM_SZ];
    u16* y3T = (u16*)(smem + Y3_OFF);
    float* cbuf = (float*)smem;          // aliases xs buf0 in epilogue

    const u16* wsT = ws;
    u32* flags = (u32*)(ws + WS_FLAGS);
    const int n = blockIdx.x & 7;
    const int h = blockIdx.x >> 3;       // 0..55
    const int tid = threadIdx.x, lane = tid & 63, wv = tid >> 6;
    const int g = wv & 3, wp = wv >> 2;
    const int q = lane >> 4, lm = lane & 15;
    const int c0 = wp * 32 + lm;         // tile-0 col (always < 48)
    const int c1 = c0 + 16;              // tile-1 col (invalid when >= 56)
    const int t0 = 9 * g;
    const int ntap = (g == 3) ? 8 : 9;   // wave-uniform

    // ---- staging: 1120 items = 5r x 16cp x 14wq; thread does <=3.
    float4 sa[3], sb[3];
#define SLOAD(CC) do {                                                        \
        _Pragma("unroll")                                                     \
        for (int u = 0; u < 3; ++u) {                                         \
            int it = tid + u * 512;                                           \
            if (it < 1120) {                                                  \
                int r = it / 224, rem = it % 224;                             \
                int cp = rem / 14, wq = rem % 14;                             \
                int gr = h - 4 + 2 * r;                                       \
                if ((unsigned)gr < BH) {                                      \
                    const float* px = x + ((size_t)(n * BC + (CC) * 32 + 2 * cp) * BH + gr) * BW + 4 * wq; \
                    sa[u] = *(const float4*)px;                               \
                    sb[u] = *(const float4*)(px + HW);                        \
                }                                                             \
            }                                                                 \
        }                                                                     \
    } while (0)

#define SWRITE(BUF) do {                                                      \
        u32* xb = (u32*)(smem + (BUF) * XSBUF);                               \
        _Pragma("unroll")                                                     \
        for (int u = 0; u < 3; ++u) {                                         \
            int it = tid + u * 512;                                           \
            if (it < 1120) {                                                  \
                int r = it / 224, rem = it % 224;                             \
                int cp = rem / 14, wq = rem % 14;                             \
                int gr = h - 4 + 2 * r;                                       \
                if ((unsigned)gr < BH) {                                      \
                    u32* d = xb + (r * 80 + 9 + 4 * wq) * 20 + cp;            \
                    d[0]  = pack2(sa[u].x, sb[u].x);                          \
                    d[20] = pack2(sa[u].y, sb[u].y);                          \
                    d[40] = pack2(sa[u].z, sb[u].z);                          \
                    d[60] = pack2(sa[u].w, sb[u].w);                          \
                }                                                             \
            }                                                                 \
        }                                                                     \
    } while (0)

    // ---- phase A: issue round-0 x loads first (longest latency) ...
    SLOAD(0);

    // ... then weight prep: one ws element per thread, blocks 0..147.
    {
        int i = blockIdx.x * 512 + tid;
        if (i < WS_WC) {
            int j = i & 7, ln = (i >> 3) & 63, r = i >> 9;     // r = cc*35+tap
            int tap = r % NTAP, cc = r / NTAP;
            int qq = ln >> 4, ll = ln & 15;
            ws[i] = f2b(w3[(ll * BC + cc * 32 + qq * 8 + j) * NTAP + tap]);
        } else if (i < WS_WC + 4096) {
            int i2 = i - WS_WC;
            int j = i2 & 7, ln = (i2 >> 3) & 63, ot = i2 >> 9;
            int qq = ln >> 4, ll = ln & 15, o = ot * 16 + ll, k = qq * 8 + j;
            float s = 0.f;
            if (k < 16)
                for (int c = 0; c < 16; ++c) s += w5[o * 16 + c] * w4[c * 16 + k];
            ws[i] = f2b(s);
        }
    }

    // ---- LDS zero prologue (round-invariant cells; disjoint writes)
    // pad cols 0..8, 65..79: 2buf x 5r x 24pc x 16cp = 3840 u32
    for (int i = tid; i < 3840; i += 512) {
        int cp = i & 15, t = i >> 4;
        int pc = t % 24, t2 = t / 24;
        int r = t2 % 5, bb = t2 / 5;
        int col = pc < 9 ? pc : 56 + pc;
        ((u32*)smem)[bb * U32BUF + (r * 80 + col) * 20 + cp] = 0u;
    }
    // invalid rows (<=2, edge blocks only): zero cols 9..64 in both bufs
    int bad0 = 0, bad1 = 0, nb = 0;
    #pragma unroll
    for (int r = 0; r < 5; ++r) {
        int gr = h - 4 + 2 * r;
        if ((unsigned)gr >= BH) { if (nb == 0) bad0 = r; else bad1 = r; ++nb; }
    }
    for (int i = tid; i < nb * 1792; i += 512) {   // 1792 = 2buf*56*16
        int cp = i & 15, t = i >> 4;
        int w = t % 56, t2 = t / 56;
        int bb = t2 & 1, r = (t2 >> 1) ? bad1 : bad0;
        ((u32*)smem)[bb * U32BUF + (r * 80 + 9 + w) * 20 + cp] = 0u;
    }
    // y3T K-pad zero: 64 rows x u32 cols 8..15, one per thread
    ((u32*)(y3T + (tid >> 3) * 40))[8 + (tid & 7)] = 0u;
    SWRITE(0);

    // ---- software grid barrier -------------------------------------------
    __threadfence();                     // this thread's ws stores -> device
    __syncthreads();                     // all threads' fences complete
    if (tid == 0)
        __hip_atomic_store(&flags[blockIdx.x], MAGIC,
                           __ATOMIC_RELEASE, __HIP_MEMORY_SCOPE_AGENT);
    // thread t monitors flag[t] (t<448); exits when all 448 are MAGIC.
    for (;;) {
        int mine = (tid >= BN * BH) ? 1 :
            (__hip_atomic_load(&flags[tid], __ATOMIC_RELAXED,
                               __HIP_MEMORY_SCOPE_AGENT) == MAGIC);
        if (__syncthreads_and(mine)) break;
        __builtin_amdgcn_s_sleep(2);
    }
    __threadfence();                     // acquire: invalidate stale L1/L2
    // ----------------------------------------------------------------------

    f32x4 acc0 = {0.f, 0.f, 0.f, 0.f};
    f32x4 acc1 = {0.f, 0.f, 0.f, 0.f};

    #pragma unroll
    for (int cc = 0; cc < 4; ++cc) {
        const int buf = cc & 1;
        // A-frags (L2/L3-broadcast from ws), issued first
        bf16x8 a[9];
        #pragma unroll
        for (int tt = 0; tt < 9; ++tt) {
            if (tt < ntap)               // wave-uniform
                a[tt] = *(const bf16x8*)(wsT + (size_t)(cc * NTAP + t0 + tt) * 512 + lane * 8);
        }
        if (cc < 3) SLOAD(cc + 1);       // next round's x loads in flight under MFMA
        const u16* xsb = (const u16*)(smem + buf * XSBUF);
        #pragma unroll
        for (int tt = 0; tt < 9; ++tt) {
            if (tt < ntap) {             // wave-uniform
                const int t = t0 + tt;
                const int kh = t / 7, kw = t - 7 * kh;
                const u16* xrow = xsb + (size_t)(kh * 80 + 3 * kw) * COLW + q * 8;
                bf16x8 b0 = *(const bf16x8*)(xrow + (size_t)c0 * COLW);
                acc0 = __builtin_amdgcn_mfma_f32_16x16x32_bf16(a[tt], b0, acc0, 0, 0, 0);
                bf16x8 b1 = *(const bf16x8*)(xrow + (size_t)c1 * COLW);
                acc1 = __builtin_amdgcn_mfma_f32_16x16x32_bf16(a[tt], b1, acc1, 0, 0, 0);
            }
        }
        if (cc < 3) {
            SWRITE(buf ^ 1);             // pack + ds_write cc+1 into other buf
            __syncthreads();             // writes visible; WAR on buf fenced
        }
    }

    // K-combine over tap-quarters. cbuf aliases xs buf0: buf0's last reads
    // were round cc=2 (fenced by its barrier); round 3 reads buf1 only.
    if (g > 0) {
        float* cb = cbuf + (size_t)(((wp * 3 + (g - 1)) * 2) * 64 + lane) * 4;
        *(f32x4*)cb = acc0;
        *(f32x4*)(cb + 256) = acc1;      // +64*4 floats = tile 1
    }
    __syncthreads();
    if (g == 0) {
        #pragma unroll
        for (int p = 0; p < 3; ++p) {
            const float* cb = cbuf + (size_t)(((wp * 3 + p) * 2) * 64 + lane) * 4;
            f32x4 v0 = *(const f32x4*)cb;
            f32x4 v1 = *(const f32x4*)(cb + 256);
            acc0[0] += v0[0]; acc0[1] += v0[1]; acc0[2] += v0[2]; acc0[3] += v0[3];
            acc1[0] += v1[0]; acc1[1] += v1[1]; acc1[2] += v1[2]; acc1[3] += v1[3];
        }
        const bool ok1 = (c1 < BW);      // c0 always valid
        *(u32*)(y3T + c0 * 40 + q * 4)     = pack2(acc0[0], acc0[1]);
        *(u32*)(y3T + c0 * 40 + q * 4 + 2) = pack2(acc0[2], acc0[3]);
        *(u32*)(y3T + c1 * 40 + q * 4)     = ok1 ? pack2(acc1[0], acc1[1]) : 0u;
        *(u32*)(y3T + c1 * 40 + q * 4 + 2) = ok1 ? pack2(acc1[2], acc1[3]) : 0u;
    }
    __syncthreads();

    // Stage-2: wave wv -> col-tile ct = wv&3, o-tiles {4*(wv>>2) .. +3}.
    const int ct = wv & 3, og = wv >> 2;
    const int wgc = ct * 16 + lm;
    bf16x8 bfrag = *(const bf16x8*)(y3T + (size_t)wgc * 40 + q * 8);
    #pragma unroll
    for (int i = 0; i < 4; ++i) {
        const int ot = 4 * og + i;
        bf16x8 afrag = *(const bf16x8*)(wsT + WS_WC + (size_t)(ot * 64 + lane) * 8);
        f32x4 c2 = {0.f, 0.f, 0.f, 0.f};
        c2 = __builtin_amdgcn_mfma_f32_16x16x32_bf16(afrag, bfrag, c2, 0, 0, 0);
        if (wgc < BW) {
            const int o = ot * 16 + q * 4;
            float* po = out + ((size_t)(n * BC + o) * BH + h) * BW + wgc;
            po[0]      = c2[0];
            po[HW]     = c2[1];
            po[2 * HW] = c2[2];
            po[3 * HW] = c2[3];
        }
    }
#undef SLOAD
#undef SWRITE
}

extern "C" void kernel_launch(void* const* d_in, const int* in_sizes, int n_in,
                              void* d_out, int out_size, void* d_ws, size_t ws_size,
                              hipStream_t stream)
{
    (void)in_sizes; (void)n_in; (void)out_size; (void)ws_size;
    const float* x  = (const float*)d_in[0];
    const float* w3 = (const float*)d_in[1];
    const float* w4 = (const float*)d_in[2];
    const float* w5 = (const float*)d_in[3];
    u16* ws = (u16*)d_ws;

    conv_fused<<<BN * BH, 512, 0, stream>>>(x, w3, w4, w5, ws, (float*)d_out);
}

// Round 7
// 88.030 us; speedup vs baseline: 2.3170x; 2.3170x over previous
//
#include <hip/hip_runtime.h>

// Problem dims
#define BN 8
#define BC 128
#define BH 56
#define BW 56
#define HW 3136
#define NTAP 35
// u16 offsets inside ws (weights only):
#define WS_WC 71680                   // stage-2 Wc fragments [WS_WC, WS_WC+4096)

typedef unsigned short u16;
typedef unsigned int u32;
typedef __bf16 bf16x8 __attribute__((ext_vector_type(8)));
typedef float f32x4 __attribute__((ext_vector_type(4)));

__device__ __forceinline__ u16 f2b(float f) {
    unsigned u = __float_as_uint(f);
    return (u16)((u + 0x7FFFu + ((u >> 16) & 1u)) >> 16);  // RNE
}
__device__ __forceinline__ u32 pack2(float a, float b) {
    return (u32)f2b(a) | ((u32)f2b(b) << 16);
}

// prep_w: weights only. 296 blocks x 256 = 75,776 threads = WS_WC + 4096.
// Builds frag-ordered w3 (wA) + folded Wc (= w5@w4, K zero-padded to 32).
// (v5/v6 fusion attempts: cooperative launch never executed under graph
// capture; software grid barrier cost ~110us in XCD-coherence spin. Two
// plain launches is the floor.)
__global__ __launch_bounds__(256) void prep_w(
    const float* __restrict__ w3, const float* __restrict__ w4,
    const float* __restrict__ w5, u16* __restrict__ ws)
{
    int i = blockIdx.x * 256 + threadIdx.x;
    if (i < WS_WC) {
        int j = i & 7, lane = (i >> 3) & 63, r = i >> 9;   // r = cc*35+tap
        int tap = r % NTAP, cc = r / NTAP;
        int q = lane >> 4, lm = lane & 15;
        ws[i] = f2b(w3[(lm * BC + cc * 32 + q * 8 + j) * NTAP + tap]);
    } else if (i < WS_WC + 4096) {
        int i2 = i - WS_WC;
        int j = i2 & 7, lane = (i2 >> 3) & 63, ot = i2 >> 9;
        int q = lane >> 4, lm = lane & 15, o = ot * 16 + lm, k = q * 8 + j;
        float s = 0.f;
        if (k < 16)
            for (int c = 0; c < 16; ++c) s += w5[o * 16 + c] * w4[c * 16 + k];
        ws[i] = f2b(s);
    }
}

// conv_mfma v7 = v4 (verified 85.4us) + SWRITE bank-conflict fix.
// v6's profile exposed SQ_LDS_BANK_CONFLICT=2.53M: with cp=rem/14 decode,
// consecutive lanes stepped wq -> LDS u32 stride 80 = 16 banks mod 32 ->
// 7-way conflict on every staging store. New decode cp=rem&15, wq=rem>>4:
// 16 lanes step cp (bank stride 1), wq pairs land {cp, cp+16} -> 2 lanes/
// bank = free. Same item set (224 = 16x14), bit-identical numerics; global
// float4 loads become 16x64B segments per instr (L2-resident, T14-hidden).
// LDS layout (bytes):
#define COLW 40                       // u16 per col (32 data + 8 pad)
#define XSBUF 32000                   // xs[5][80][COLW] u16
#define U32BUF 8000                   // XSBUF/4
#define Y3_OFF 64000                  // y3T[64][40] u16 = 5120
#define SMEM_SZ 69632                 // 69120 + 512 slack (benign masked-lane
                                      // col-overrun reads); 2 blocks/CU

__global__ __launch_bounds__(512, 4) void conv_mfma(
    const float* __restrict__ x, const u16* __restrict__ wsT,
    float* __restrict__ out)
{
    __shared__ __align__(16) char smem[SMEM_SZ];
    u16* y3T = (u16*)(smem + Y3_OFF);
    float* cbuf = (float*)smem;          // aliases xs buf0 in epilogue

    const int n = blockIdx.x & 7;
    const int h = blockIdx.x >> 3;       // 0..55
    const int tid = threadIdx.x, lane = tid & 63, wv = tid >> 6;
    const int g = wv & 3, wp = wv >> 2;
    const int q = lane >> 4, lm = lane & 15;
    const int c0 = wp * 32 + lm;         // tile-0 col (always < 48)
    const int c1 = c0 + 16;              // tile-1 col (invalid when >= 56)
    const int t0 = 9 * g;
    const int ntap = (g == 3) ? 8 : 9;   // wave-uniform

    // ---- staging: 1120 items = 5r x 14wq x 16cp (cp fastest); thread <=3.
    float4 sa[3], sb[3];
#define SLOAD(CC) do {                                                        \
        _Pragma("unroll")                                                     \
        for (int u = 0; u < 3; ++u) {                                         \
            int it = tid + u * 512;                                           \
            if (it < 1120) {                                                  \
                int r = it / 224, rem = it % 224;                             \
                int cp = rem & 15, wq = rem >> 4;                             \
                int gr = h - 4 + 2 * r;                                       \
                if ((unsigned)gr < BH) {                                      \
                    const float* px = x + ((size_t)(n * BC + (CC) * 32 + 2 * cp) * BH + gr) * BW + 4 * wq; \
                    sa[u] = *(const float4*)px;                               \
                    sb[u] = *(const float4*)(px + HW);                        \
                }                                                             \
            }                                                                 \
        }                                                                     \
    } while (0)

#define SWRITE(BUF) do {                                                      \
        u32* xb = (u32*)(smem + (BUF) * XSBUF);                               \
        _Pragma("unroll")                                                     \
        for (int u = 0; u < 3; ++u) {                                         \
            int it = tid + u * 512;                                           \
            if (it < 1120) {                                                  \
                int r = it / 224, rem = it % 224;                             \
                int cp = rem & 15, wq = rem >> 4;                             \
                int gr = h - 4 + 2 * r;                                       \
                if ((unsigned)gr < BH) {                                      \
                    u32* d = xb + (r * 80 + 9 + 4 * wq) * 20 + cp;            \
                    d[0]  = pack2(sa[u].x, sb[u].x);                          \
                    d[20] = pack2(sa[u].y, sb[u].y);                          \
                    d[40] = pack2(sa[u].z, sb[u].z);                          \
                    d[60] = pack2(sa[u].w, sb[u].w);                          \
                }                                                             \
            }                                                                 \
        }                                                                     \
    } while (0)

    // ---- prologue: zeros (round-invariant cells) + round-0 stage.
    SLOAD(0);
    // pad cols 0..8, 65..79: 2buf x 5r x 24pc x 16cp = 3840 u32
    for (int i = tid; i < 3840; i += 512) {
        int cp = i & 15, t = i >> 4;
        int pc = t % 24, t2 = t / 24;
        int r = t2 % 5, bb = t2 / 5;
        int col = pc < 9 ? pc : 56 + pc;
        ((u32*)smem)[bb * U32BUF + (r * 80 + col) * 20 + cp] = 0u;
    }
    // invalid rows (<=2, edge blocks only): zero cols 9..64 in both bufs
    int bad0 = 0, bad1 = 0, nb = 0;
    #pragma unroll
    for (int r = 0; r < 5; ++r) {
        int gr = h - 4 + 2 * r;
        if ((unsigned)gr >= BH) { if (nb == 0) bad0 = r; else bad1 = r; ++nb; }
    }
    for (int i = tid; i < nb * 1792; i += 512) {   // 1792 = 2buf*56*16
        int cp = i & 15, t = i >> 4;
        int w = t % 56, t2 = t / 56;
        int bb = t2 & 1, r = (t2 >> 1) ? bad1 : bad0;
        ((u32*)smem)[bb * U32BUF + (r * 80 + 9 + w) * 20 + cp] = 0u;
    }
    // y3T K-pad zero: 64 rows x u32 cols 8..15, one per thread
    ((u32*)(y3T + (tid >> 3) * 40))[8 + (tid & 7)] = 0u;
    SWRITE(0);
    __syncthreads();                     // zeros + round-0 data visible

    f32x4 acc0 = {0.f, 0.f, 0.f, 0.f};
    f32x4 acc1 = {0.f, 0.f, 0.f, 0.f};

    #pragma unroll
    for (int cc = 0; cc < 4; ++cc) {
        const int buf = cc & 1;
        // A-frags (L2-broadcast from ws), issued first
        bf16x8 a[9];
        #pragma unroll
        for (int tt = 0; tt < 9; ++tt) {
            if (tt < ntap)               // wave-uniform
                a[tt] = *(const bf16x8*)(wsT + (size_t)(cc * NTAP + t0 + tt) * 512 + lane * 8);
        }
        if (cc < 3) SLOAD(cc + 1);       // next round's x loads in flight under MFMA
        const u16* xsb = (const u16*)(smem + buf * XSBUF);
        #pragma unroll
        for (int tt = 0; tt < 9; ++tt) {
            if (tt < ntap) {             // wave-uniform
                const int t = t0 + tt;
                const int kh = t / 7, kw = t - 7 * kh;
                const u16* xrow = xsb + (size_t)(kh * 80 + 3 * kw) * COLW + q * 8;
                bf16x8 b0 = *(const bf16x8*)(xrow + (size_t)c0 * COLW);
                acc0 = __builtin_amdgcn_mfma_f32_16x16x32_bf16(a[tt], b0, acc0, 0, 0, 0);
                bf16x8 b1 = *(const bf16x8*)(xrow + (size_t)c1 * COLW);
                acc1 = __builtin_amdgcn_mfma_f32_16x16x32_bf16(a[tt], b1, acc1, 0, 0, 0);
            }
        }
        if (cc < 3) {
            SWRITE(buf ^ 1);             // pack + ds_write cc+1 into other buf
            __syncthreads();             // writes visible; WAR on buf fenced
        }
    }

    // K-combine over tap-quarters. cbuf aliases xs buf0: buf0's last reads
    // were round cc=2 (fenced by its barrier); round 3 reads buf1 only.
    if (g > 0) {
        float* cb = cbuf + (size_t)(((wp * 3 + (g - 1)) * 2) * 64 + lane) * 4;
        *(f32x4*)cb = acc0;
        *(f32x4*)(cb + 256) = acc1;      // +64*4 floats = tile 1
    }
    __syncthreads();
    if (g == 0) {
        #pragma unroll
        for (int p = 0; p < 3; ++p) {
            const float* cb = cbuf + (size_t)(((wp * 3 + p) * 2) * 64 + lane) * 4;
            f32x4 v0 = *(const f32x4*)cb;
            f32x4 v1 = *(const f32x4*)(cb + 256);
            acc0[0] += v0[0]; acc0[1] += v0[1]; acc0[2] += v0[2]; acc0[3] += v0[3];
            acc1[0] += v1[0]; acc1[1] += v1[1]; acc1[2] += v1[2]; acc1[3] += v1[3];
        }
        const bool ok1 = (c1 < BW);      // c0 always valid
        *(u32*)(y3T + c0 * 40 + q * 4)     = pack2(acc0[0], acc0[1]);
        *(u32*)(y3T + c0 * 40 + q * 4 + 2) = pack2(acc0[2], acc0[3]);
        *(u32*)(y3T + c1 * 40 + q * 4)     = ok1 ? pack2(acc1[0], acc1[1]) : 0u;
        *(u32*)(y3T + c1 * 40 + q * 4 + 2) = ok1 ? pack2(acc1[2], acc1[3]) : 0u;
    }
    __syncthreads();

    // Stage-2: wave wv -> col-tile ct = wv&3, o-tiles {4*(wv>>2) .. +3}.
    const int ct = wv & 3, og = wv >> 2;
    const int wgc = ct * 16 + lm;
    bf16x8 bfrag = *(const bf16x8*)(y3T + (size_t)wgc * 40 + q * 8);
    #pragma unroll
    for (int i = 0; i < 4; ++i) {
        const int ot = 4 * og + i;
        bf16x8 afrag = *(const bf16x8*)(wsT + WS_WC + (size_t)(ot * 64 + lane) * 8);
        f32x4 c2 = {0.f, 0.f, 0.f, 0.f};
        c2 = __builtin_amdgcn_mfma_f32_16x16x32_bf16(afrag, bfrag, c2, 0, 0, 0);
        if (wgc < BW) {
            const int o = ot * 16 + q * 4;
            float* po = out + ((size_t)(n * BC + o) * BH + h) * BW + wgc;
            po[0]      = c2[0];
            po[HW]     = c2[1];
            po[2 * HW] = c2[2];
            po[3 * HW] = c2[3];
        }
    }
#undef SLOAD
#undef SWRITE
}

extern "C" void kernel_launch(void* const* d_in, const int* in_sizes, int n_in,
                              void* d_out, int out_size, void* d_ws, size_t ws_size,
                              hipStream_t stream)
{
    (void)in_sizes; (void)n_in; (void)out_size; (void)ws_size;
    const float* x  = (const float*)d_in[0];
    const float* w3 = (const float*)d_in[1];
    const float* w4 = (const float*)d_in[2];
    const float* w5 = (const float*)d_in[3];
    u16* ws = (u16*)d_ws;

    prep_w<<<296, 256, 0, stream>>>(w3, w4, w5, ws);
    conv_mfma<<<BN * BH, 512, 0, stream>>>(x, ws, (float*)d_out);
}

// Round 8
// 84.981 us; speedup vs baseline: 2.4002x; 1.0359x over previous
//
#include <hip/hip_runtime.h>

// Problem dims
#define BN 8
#define BC 128
#define BH 56
#define BW 56
#define HW 3136
#define NTAP 35
// u16 offsets inside ws (weights only):
#define WS_WC 71680                   // stage-2 Wc fragments [WS_WC, WS_WC+4096)

typedef unsigned short u16;
typedef unsigned int u32;
typedef __bf16 bf16x8 __attribute__((ext_vector_type(8)));
typedef float f32x4 __attribute__((ext_vector_type(4)));

__device__ __forceinline__ u16 f2b(float f) {
    unsigned u = __float_as_uint(f);
    return (u16)((u + 0x7FFFu + ((u >> 16) & 1u)) >> 16);  // RNE
}
__device__ __forceinline__ u32 pack2(float a, float b) {
    return (u32)f2b(a) | ((u32)f2b(b) << 16);
}

// prep_w: weights only. 296 blocks x 256 = 75,776 threads = WS_WC + 4096.
// Builds frag-ordered w3 (wA) + folded Wc (= w5@w4, K zero-padded to 32).
// Session notes: cooperative launch never executes under graph capture
// (v5); software grid barrier costs ~110us in cross-XCD coherence spin
// (v6); SWRITE cp-fastest decode fixes LDS banks but breaks global
// coalescing, net regression (v7). Two plain launches + this v4 structure
// is the verified floor (85.4us).
__global__ __launch_bounds__(256) void prep_w(
    const float* __restrict__ w3, const float* __restrict__ w4,
    const float* __restrict__ w5, u16* __restrict__ ws)
{
    int i = blockIdx.x * 256 + threadIdx.x;
    if (i < WS_WC) {
        int j = i & 7, lane = (i >> 3) & 63, r = i >> 9;   // r = cc*35+tap
        int tap = r % NTAP, cc = r / NTAP;
        int q = lane >> 4, lm = lane & 15;
        ws[i] = f2b(w3[(lm * BC + cc * 32 + q * 8 + j) * NTAP + tap]);
    } else if (i < WS_WC + 4096) {
        int i2 = i - WS_WC;
        int j = i2 & 7, lane = (i2 >> 3) & 63, ot = i2 >> 9;
        int q = lane >> 4, lm = lane & 15, o = ot * 16 + lm, k = q * 8 + j;
        float s = 0.f;
        if (k < 16)
            for (int c = 0; c < 16; ++c) s += w5[o * 16 + c] * w4[c * 16 + k];
        ws[i] = f2b(s);
    }
}

// conv_mfma v4 (verified 85.4us — best of session; restored after v7's
// decode experiment regressed). Fused im2row: blocks read x directly
// (L2-local per XCD: n = blockIdx&7). 448 blocks (n,h) x 512 threads
// (8 waves). Wave wv = (wp=wv>>2 col-pair, g=wv&3 tap-quarter 9/9/9/8);
// each wave owns two 16-col tiles (A-frag reused). Staging register-split
// (T14): SLOAD(cc+1) before compute(cc), pack2+ds_write after; one barrier
// per round; double-buffered xs. Known cost (accepted): SWRITE's wq-fastest
// decode is a 7-way LDS bank conflict, but the alternative (cp-fastest)
// un-coalesces the global loads and measured worse (v7: 88.0).
// LDS layout (bytes):
#define COLW 40                       // u16 per col (32 data + 8 pad)
#define XSBUF 32000                   // xs[5][80][COLW] u16
#define U32BUF 8000                   // XSBUF/4
#define Y3_OFF 64000                  // y3T[64][40] u16 = 5120
#define SMEM_SZ 69632                 // 69120 + 512 slack (benign masked-lane
                                      // col-overrun reads); 2 blocks/CU

__global__ __launch_bounds__(512, 4) void conv_mfma(
    const float* __restrict__ x, const u16* __restrict__ wsT,
    float* __restrict__ out)
{
    __shared__ __align__(16) char smem[SMEM_SZ];
    u16* y3T = (u16*)(smem + Y3_OFF);
    float* cbuf = (float*)smem;          // aliases xs buf0 in epilogue

    const int n = blockIdx.x & 7;
    const int h = blockIdx.x >> 3;       // 0..55
    const int tid = threadIdx.x, lane = tid & 63, wv = tid >> 6;
    const int g = wv & 3, wp = wv >> 2;
    const int q = lane >> 4, lm = lane & 15;
    const int c0 = wp * 32 + lm;         // tile-0 col (always < 48)
    const int c1 = c0 + 16;              // tile-1 col (invalid when >= 56)
    const int t0 = 9 * g;
    const int ntap = (g == 3) ? 8 : 9;   // wave-uniform

    // ---- staging: 1120 items = 5r x 16cp x 14wq; thread does <=3.
    float4 sa[3], sb[3];
#define SLOAD(CC) do {                                                        \
        _Pragma("unroll")                                                     \
        for (int u = 0; u < 3; ++u) {                                         \
            int it = tid + u * 512;                                           \
            if (it < 1120) {                                                  \
                int r = it / 224, rem = it % 224;                             \
                int cp = rem / 14, wq = rem % 14;                             \
                int gr = h - 4 + 2 * r;                                       \
                if ((unsigned)gr < BH) {                                      \
                    const float* px = x + ((size_t)(n * BC + (CC) * 32 + 2 * cp) * BH + gr) * BW + 4 * wq; \
                    sa[u] = *(const float4*)px;                               \
                    sb[u] = *(const float4*)(px + HW);                        \
                }                                                             \
            }                                                                 \
        }                                                                     \
    } while (0)

#define SWRITE(BUF) do {                                                      \
        u32* xb = (u32*)(smem + (BUF) * XSBUF);                               \
        _Pragma("unroll")                                                     \
        for (int u = 0; u < 3; ++u) {                                         \
            int it = tid + u * 512;                                           \
            if (it < 1120) {                                                  \
                int r = it / 224, rem = it % 224;                             \
                int cp = rem / 14, wq = rem % 14;                             \
                int gr = h - 4 + 2 * r;                                       \
                if ((unsigned)gr < BH) {                                      \
                    u32* d = xb + (r * 80 + 9 + 4 * wq) * 20 + cp;            \
                    d[0]  = pack2(sa[u].x, sb[u].x);                          \
                    d[20] = pack2(sa[u].y, sb[u].y);                          \
                    d[40] = pack2(sa[u].z, sb[u].z);                          \
                    d[60] = pack2(sa[u].w, sb[u].w);                          \
                }                                                             \
            }                                                                 \
        }                                                                     \
    } while (0)

    // ---- prologue: zeros (round-invariant cells) + round-0 stage.
    SLOAD(0);
    // pad cols 0..8, 65..79: 2buf x 5r x 24pc x 16cp = 3840 u32
    for (int i = tid; i < 3840; i += 512) {
        int cp = i & 15, t = i >> 4;
        int pc = t % 24, t2 = t / 24;
        int r = t2 % 5, bb = t2 / 5;
        int col = pc < 9 ? pc : 56 + pc;
        ((u32*)smem)[bb * U32BUF + (r * 80 + col) * 20 + cp] = 0u;
    }
    // invalid rows (<=2, edge blocks only): zero cols 9..64 in both bufs
    int bad0 = 0, bad1 = 0, nb = 0;
    #pragma unroll
    for (int r = 0; r < 5; ++r) {
        int gr = h - 4 + 2 * r;
        if ((unsigned)gr >= BH) { if (nb == 0) bad0 = r; else bad1 = r; ++nb; }
    }
    for (int i = tid; i < nb * 1792; i += 512) {   // 1792 = 2buf*56*16
        int cp = i & 15, t = i >> 4;
        int w = t % 56, t2 = t / 56;
        int bb = t2 & 1, r = (t2 >> 1) ? bad1 : bad0;
        ((u32*)smem)[bb * U32BUF + (r * 80 + 9 + w) * 20 + cp] = 0u;
    }
    // y3T K-pad zero: 64 rows x u32 cols 8..15, one per thread
    ((u32*)(y3T + (tid >> 3) * 40))[8 + (tid & 7)] = 0u;
    SWRITE(0);
    __syncthreads();                     // zeros + round-0 data visible

    f32x4 acc0 = {0.f, 0.f, 0.f, 0.f};
    f32x4 acc1 = {0.f, 0.f, 0.f, 0.f};

    #pragma unroll
    for (int cc = 0; cc < 4; ++cc) {
        const int buf = cc & 1;
        // A-frags (L2-broadcast from ws), issued first
        bf16x8 a[9];
        #pragma unroll
        for (int tt = 0; tt < 9; ++tt) {
            if (tt < ntap)               // wave-uniform
                a[tt] = *(const bf16x8*)(wsT + (size_t)(cc * NTAP + t0 + tt) * 512 + lane * 8);
        }
        if (cc < 3) SLOAD(cc + 1);       // next round's x loads in flight under MFMA
        const u16* xsb = (const u16*)(smem + buf * XSBUF);
        #pragma unroll
        for (int tt = 0; tt < 9; ++tt) {
            if (tt < ntap) {             // wave-uniform
                const int t = t0 + tt;
                const int kh = t / 7, kw = t - 7 * kh;
                const u16* xrow = xsb + (size_t)(kh * 80 + 3 * kw) * COLW + q * 8;
                bf16x8 b0 = *(const bf16x8*)(xrow + (size_t)c0 * COLW);
                acc0 = __builtin_amdgcn_mfma_f32_16x16x32_bf16(a[tt], b0, acc0, 0, 0, 0);
                bf16x8 b1 = *(const bf16x8*)(xrow + (size_t)c1 * COLW);
                acc1 = __builtin_amdgcn_mfma_f32_16x16x32_bf16(a[tt], b1, acc1, 0, 0, 0);
            }
        }
        if (cc < 3) {
            SWRITE(buf ^ 1);             // pack + ds_write cc+1 into other buf
            __syncthreads();             // writes visible; WAR on buf fenced
        }
    }

    // K-combine over tap-quarters. cbuf aliases xs buf0: buf0's last reads
    // were round cc=2 (fenced by its barrier); round 3 reads buf1 only.
    if (g > 0) {
        float* cb = cbuf + (size_t)(((wp * 3 + (g - 1)) * 2) * 64 + lane) * 4;
        *(f32x4*)cb = acc0;
        *(f32x4*)(cb + 256) = acc1;      // +64*4 floats = tile 1
    }
    __syncthreads();
    if (g == 0) {
        #pragma unroll
        for (int p = 0; p < 3; ++p) {
            const float* cb = cbuf + (size_t)(((wp * 3 + p) * 2) * 64 + lane) * 4;
            f32x4 v0 = *(const f32x4*)cb;
            f32x4 v1 = *(const f32x4*)(cb + 256);
            acc0[0] += v0[0]; acc0[1] += v0[1]; acc0[2] += v0[2]; acc0[3] += v0[3];
            acc1[0] += v1[0]; acc1[1] += v1[1]; acc1[2] += v1[2]; acc1[3] += v1[3];
        }
        const bool ok1 = (c1 < BW);      // c0 always valid
        *(u32*)(y3T + c0 * 40 + q * 4)     = pack2(acc0[0], acc0[1]);
        *(u32*)(y3T + c0 * 40 + q * 4 + 2) = pack2(acc0[2], acc0[3]);
        *(u32*)(y3T + c1 * 40 + q * 4)     = ok1 ? pack2(acc1[0], acc1[1]) : 0u;
        *(u32*)(y3T + c1 * 40 + q * 4 + 2) = ok1 ? pack2(acc1[2], acc1[3]) : 0u;
    }
    __syncthreads();

    // Stage-2: wave wv -> col-tile ct = wv&3, o-tiles {4*(wv>>2) .. +3}.
    const int ct = wv & 3, og = wv >> 2;
    const int wgc = ct * 16 + lm;
    bf16x8 bfrag = *(const bf16x8*)(y3T + (size_t)wgc * 40 + q * 8);
    #pragma unroll
    for (int i = 0; i < 4; ++i) {
        const int ot = 4 * og + i;
        bf16x8 afrag = *(const bf16x8*)(wsT + WS_WC + (size_t)(ot * 64 + lane) * 8);
        f32x4 c2 = {0.f, 0.f, 0.f, 0.f};
        c2 = __builtin_amdgcn_mfma_f32_16x16x32_bf16(afrag, bfrag, c2, 0, 0, 0);
        if (wgc < BW) {
            const int o = ot * 16 + q * 4;
            float* po = out + ((size_t)(n * BC + o) * BH + h) * BW + wgc;
            po[0]      = c2[0];
            po[HW]     = c2[1];
            po[2 * HW] = c2[2];
            po[3 * HW] = c2[3];
        }
    }
#undef SLOAD
#undef SWRITE
}

extern "C" void kernel_launch(void* const* d_in, const int* in_sizes, int n_in,
                              void* d_out, int out_size, void* d_ws, size_t ws_size,
                              hipStream_t stream)
{
    (void)in_sizes; (void)n_in; (void)out_size; (void)ws_size;
    const float* x  = (const float*)d_in[0];
    const float* w3 = (const float*)d_in[1];
    const float* w4 = (const float*)d_in[2];
    const float* w5 = (const float*)d_in[3];
    u16* ws = (u16*)d_ws;

    prep_w<<<296, 256, 0, stream>>>(w3, w4, w5, ws);
    conv_mfma<<<BN * BH, 512, 0, stream>>>(x, ws, (float*)d_out);
}